// Round 9
// baseline (189.513 us; speedup 1.0000x reference)
//
#include <hip/hip_runtime.h>

namespace {
constexpr int kB = 64;
constexpr int kM = 4096;
constexpr int kN = 8192;
constexpr int kBM = kB * kM;   // 262144
constexpr int kBN = kB * kN;   // 524288
constexpr int kG  = 4;         // chunks (blocks) per instance
constexpr int kRBlocks = 1024; // reduce grid size
constexpr float W_PRIMAL = 0.1f;
constexpr float W_DUAL   = 0.1f;
constexpr float W_STAT   = 0.6f;
constexpr float W_COMP   = 0.2f;
// Fixed-point scale for LDS integer accumulation. Final per-element sums are
// bounded by ~31 (4.7 sigma of a 39-term product-normal sum); 2^31/2^25 = 64
// gives 2x headroom. Wrapping u32 adds are exact mod 2^32. Verified r8:
// absmax 0.0 vs np ref.
constexpr float kScale    = 33554432.0f;        // 2^25
constexpr float kInvScale = 1.0f / 33554432.0f;
}

// -------- scatter, LDS-resident, integer fixed-point LDS atomics --------
// Measured r8: ds_add_u32 runs ~1 cyc/lane (vs 3.5 for any fp32 LDS atomic
// variant) -> scatter 116 -> 45 us. The LDS RMW engine is lane-serial; the
// 20.5M lane-atomics give a 33 us chip floor; 45 us = floor + conflicts
// (12.6K cyc/CU) + staging. Structure-insensitive (r2-r5).
__global__ __launch_bounds__(1024, 4) void kkt_scatter(
    const float* __restrict__ a_vals,
    const int*   __restrict__ a_rows,
    const int*   __restrict__ a_cols,
    const float* __restrict__ x_hat,
    const float* __restrict__ lam_hat,
    float* __restrict__ P_ax,     // [kG][kBM]
    float* __restrict__ P_at,     // [kG][kBN]
    unsigned* __restrict__ ctr,   // arrive counter for reduce (zeroed here)
    int nnz_per)
{
    __shared__ float    s_x  [kN];  // 32 KB  instance x slice
    __shared__ float    s_lam[kM];  // 16 KB  instance lam slice
    __shared__ unsigned s_axi[kM];  // 16 KB  fixed-point accumulator
    __shared__ unsigned s_ati[kN];  // 32 KB  fixed-point accumulator (96 KB)

    const int tid = threadIdx.x;
    const int bs  = blockDim.x;
    const int k   = blockIdx.x / kG;
    const int g   = blockIdx.x % kG;
    const int row_base = k * kM;
    const int col_base = k * kN;

    // zero the reduce kernel's arrive counter (stream order makes it visible)
    if (blockIdx.x == 0 && tid == 0) ctr[0] = 0u;

    // cooperative load of x/lam slices (coalesced float4) + zero accumulators
    {
        const float4* xg = reinterpret_cast<const float4*>(x_hat + col_base);
        const float4* lg = reinterpret_cast<const float4*>(lam_hat + row_base);
        float4* xs = reinterpret_cast<float4*>(s_x);
        float4* ls = reinterpret_cast<float4*>(s_lam);
        for (int j = tid; j < kN / 4; j += bs) xs[j] = xg[j];
        for (int j = tid; j < kM / 4; j += bs) ls[j] = lg[j];
        uint4 z = {0u, 0u, 0u, 0u};
        uint4* as = reinterpret_cast<uint4*>(s_axi);
        uint4* ts = reinterpret_cast<uint4*>(s_ati);
        for (int j = tid; j < kM / 4; j += bs) as[j] = z;
        for (int j = tid; j < kN / 4; j += bs) ts[j] = z;
    }
    __syncthreads();

    const int chunk = nnz_per / kG;        // 40000
    const int base  = k * nnz_per + g * chunk;
    const int nq    = chunk >> 2;
    const int qbase = base >> 2;           // base % 4 == 0 for this shape

    const float4* v4 = reinterpret_cast<const float4*>(a_vals);
    const int4*   r4 = reinterpret_cast<const int4*>(a_rows);
    const int4*   c4 = reinterpret_cast<const int4*>(a_cols);

    for (int q = tid; q < nq; q += bs) {
        float4 v = v4[qbase + q];
        int4   r = r4[qbase + q];
        int4   c = c4[qbase + q];
        int rl0 = r.x - row_base, rl1 = r.y - row_base,
            rl2 = r.z - row_base, rl3 = r.w - row_base;
        int cl0 = c.x - col_base, cl1 = c.y - col_base,
            cl2 = c.z - col_base, cl3 = c.w - col_base;
        float x0 = s_x[cl0], x1 = s_x[cl1], x2 = s_x[cl2], x3 = s_x[cl3];
        float l0 = s_lam[rl0], l1 = s_lam[rl1], l2 = s_lam[rl2], l3 = s_lam[rl3];
        int qa0 = (int)rintf(v.x * x0 * kScale);
        int qa1 = (int)rintf(v.y * x1 * kScale);
        int qa2 = (int)rintf(v.z * x2 * kScale);
        int qa3 = (int)rintf(v.w * x3 * kScale);
        int qt0 = (int)rintf(v.x * l0 * kScale);
        int qt1 = (int)rintf(v.y * l1 * kScale);
        int qt2 = (int)rintf(v.z * l2 * kScale);
        int qt3 = (int)rintf(v.w * l3 * kScale);
        atomicAdd(&s_axi[rl0], (unsigned)qa0);
        atomicAdd(&s_axi[rl1], (unsigned)qa1);
        atomicAdd(&s_axi[rl2], (unsigned)qa2);
        atomicAdd(&s_axi[rl3], (unsigned)qa3);
        atomicAdd(&s_ati[cl0], (unsigned)qt0);
        atomicAdd(&s_ati[cl1], (unsigned)qt1);
        atomicAdd(&s_ati[cl2], (unsigned)qt2);
        atomicAdd(&s_ati[cl3], (unsigned)qt3);
    }
    // scalar tail (never runs when chunk % 4 == 0; kept for safety)
    if ((chunk & 3) && g == kG - 1 && tid == 0) {
        for (int i = base + (nq << 2); i < base + chunk; ++i) {
            float v = a_vals[i];
            int qa = (int)rintf(v * s_x[a_cols[i] - col_base] * kScale);
            int qt = (int)rintf(v * s_lam[a_rows[i] - row_base] * kScale);
            atomicAdd(&s_axi[a_rows[i] - row_base], (unsigned)qa);
            atomicAdd(&s_ati[a_cols[i] - col_base], (unsigned)qt);
        }
    }
    __syncthreads();

    // convert fixed->float during the coalesced partial store
    {
        float4* pa = reinterpret_cast<float4*>(P_ax + (size_t)g * kBM + row_base);
        float4* pt = reinterpret_cast<float4*>(P_at + (size_t)g * kBN + col_base);
        const uint4* as = reinterpret_cast<const uint4*>(s_axi);
        const uint4* ts = reinterpret_cast<const uint4*>(s_ati);
        for (int j = tid; j < kM / 4; j += bs) {
            uint4 u = as[j];
            float4 o = {(float)(int)u.x * kInvScale, (float)(int)u.y * kInvScale,
                        (float)(int)u.z * kInvScale, (float)(int)u.w * kInvScale};
            pa[j] = o;
        }
        for (int j = tid; j < kN / 4; j += bs) {
            uint4 u = ts[j];
            float4 o = {(float)(int)u.x * kInvScale, (float)(int)u.y * kInvScale,
                        (float)(int)u.z * kInvScale, (float)(int)u.w * kInvScale};
            pt[j] = o;
        }
    }
}

// -------- fused reduction + last-block finalize (saves the 3rd dispatch) --------
__device__ __forceinline__ float block_reduce_sum(float v)
{
    __shared__ float smem[16];
    int lane = threadIdx.x & 63;
    int wave = threadIdx.x >> 6;
    #pragma unroll
    for (int off = 32; off > 0; off >>= 1)
        v += __shfl_down(v, off, 64);
    if (lane == 0) smem[wave] = v;
    __syncthreads();
    float s = 0.f;
    if (threadIdx.x == 0) {
        int nw = blockDim.x >> 6;
        for (int w = 0; w < nw; ++w) s += smem[w];
    }
    return s;  // valid only on thread 0
}

__global__ void kkt_reduce(const float* __restrict__ P_ax,
                           const float* __restrict__ P_at,
                           const float* __restrict__ b_pad,
                           const float* __restrict__ lam_hat,
                           const float* __restrict__ c_pad,
                           const float* __restrict__ x_hat,
                           float* __restrict__ partials,
                           unsigned* __restrict__ ctr,
                           float* __restrict__ out)
{
    const int mq = kBM / 4;
    const int nq = kBN / 4;
    float s1 = 0.f;                  // weight 1/((M+N)*B)
    float s2 = 0.f;                  // weight W_STAT/(N*B)
    const int stride = gridDim.x * blockDim.x;
    for (int idx = blockIdx.x * blockDim.x + threadIdx.x; idx < mq + nq; idx += stride) {
        if (idx < mq) {
            float4 ax = reinterpret_cast<const float4*>(P_ax)[idx];
            #pragma unroll
            for (int g = 1; g < kG; ++g) {
                float4 p = reinterpret_cast<const float4*>(P_ax + (size_t)g * kBM)[idx];
                ax.x += p.x; ax.y += p.y; ax.z += p.z; ax.w += p.w;
            }
            float4 bb = reinterpret_cast<const float4*>(b_pad)[idx];
            float4 ll = reinterpret_cast<const float4*>(lam_hat)[idx];
            #pragma unroll
            for (int e = 0; e < 4; ++e) {
                float axmb = (&ax.x)[e] - (&bb.x)[e];
                float l    = (&ll.x)[e];
                float rp   = fmaxf(axmb, 0.f);
                float rl   = fmaxf(-l, 0.f);
                float cm   = l * axmb;
                s1 += W_PRIMAL * rp * rp + W_DUAL * rl * rl + W_COMP * cm * cm;
            }
        } else {
            int j = idx - mq;
            float4 at = reinterpret_cast<const float4*>(P_at)[j];
            #pragma unroll
            for (int g = 1; g < kG; ++g) {
                float4 p = reinterpret_cast<const float4*>(P_at + (size_t)g * kBN)[j];
                at.x += p.x; at.y += p.y; at.z += p.z; at.w += p.w;
            }
            float4 cc = reinterpret_cast<const float4*>(c_pad)[j];
            float4 xx = reinterpret_cast<const float4*>(x_hat)[j];
            #pragma unroll
            for (int e = 0; e < 4; ++e) {
                float t  = (&at.x)[e] + (&cc.x)[e];
                float mu = fmaxf(t, 0.f);
                float st = t - mu;                 // min(t,0); dual relu(-mu)^2 == 0
                float x  = (&xx.x)[e];
                float rx = fmaxf(-x, 0.f);
                float cm = mu * x;
                s1 += W_PRIMAL * rx * rx + W_COMP * cm * cm;
                s2 += st * st;
            }
        }
    }
    const float scale1 = 1.0f / ((float)(kM + kN) * (float)kB);
    const float scale2 = W_STAT / ((float)kN * (float)kB);
    float t = block_reduce_sum(s1 * scale1 + s2 * scale2);

    // last arriving block sums all partials (r7-verified atomics scheme)
    __shared__ int is_last;
    if (threadIdx.x == 0) {
        __hip_atomic_store(&partials[blockIdx.x], t, __ATOMIC_RELAXED,
                           __HIP_MEMORY_SCOPE_AGENT);
        unsigned old = __hip_atomic_fetch_add(&ctr[0], 1u, __ATOMIC_ACQ_REL,
                                              __HIP_MEMORY_SCOPE_AGENT);
        is_last = (old == (unsigned)(gridDim.x - 1)) ? 1 : 0;
    }
    __syncthreads();
    if (is_last) {
        float v = 0.f;
        for (int j = threadIdx.x; j < (int)gridDim.x; j += blockDim.x)
            v += __hip_atomic_load(&partials[j], __ATOMIC_RELAXED,
                                   __HIP_MEMORY_SCOPE_AGENT);
        __syncthreads();   // smem of block_reduce_sum reused
        float tot = block_reduce_sum(v);
        if (threadIdx.x == 0) out[0] = tot;
    }
}

extern "C" void kernel_launch(void* const* d_in, const int* in_sizes, int n_in,
                              void* d_out, int out_size, void* d_ws, size_t ws_size,
                              hipStream_t stream)
{
    const float* x_hat   = (const float*)d_in[0];
    const float* lam_hat = (const float*)d_in[1];
    const float* a_vals  = (const float*)d_in[2];
    const int*   a_rows  = (const int*)d_in[3];
    const int*   a_cols  = (const int*)d_in[4];
    const float* b_pad   = (const float*)d_in[5];
    const float* c_pad   = (const float*)d_in[6];
    float* out = (float*)d_out;

    const int nnz     = in_sizes[2];
    const int nnz_per = nnz / kB;

    float*    P_ax     = (float*)d_ws;                    // kG*kBM floats (4 MB)
    float*    P_at     = P_ax + (size_t)kG * kBM;         // kG*kBN floats (8 MB)
    float*    partials = P_at + (size_t)kG * kBN;         // kRBlocks floats
    unsigned* ctr      = (unsigned*)(partials + kRBlocks);

    kkt_scatter<<<dim3(kB * kG), dim3(1024), 0, stream>>>(
        a_vals, a_rows, a_cols, x_hat, lam_hat, P_ax, P_at, ctr, nnz_per);

    kkt_reduce<<<dim3(kRBlocks), dim3(256), 0, stream>>>(
        P_ax, P_at, b_pad, lam_hat, c_pad, x_hat, partials, ctr, out);
}

// Round 10
// 163.148 us; speedup vs baseline: 1.1616x; 1.1616x over previous
//
#include <hip/hip_runtime.h>

namespace {
constexpr int kB = 64;
constexpr int kM = 4096;
constexpr int kN = 8192;
constexpr int kBM = kB * kM;   // 262144
constexpr int kBN = kB * kN;   // 524288
constexpr int kG  = 4;         // chunks (blocks) per instance
constexpr int kRBlocks = 1024; // reduce grid size (must match finalize)
constexpr float W_PRIMAL = 0.1f;
constexpr float W_DUAL   = 0.1f;
constexpr float W_STAT   = 0.6f;
constexpr float W_COMP   = 0.2f;
// Fixed-point scale for LDS integer accumulation. Final per-element sums are
// bounded by ~31 (4.7 sigma of a 39-term product-normal sum); 2^31/2^25 = 64
// gives 2x headroom. Wrapping u32 adds are exact mod 2^32. Verified r8/r9:
// absmax 0.0 vs np ref.
constexpr float kScale    = 33554432.0f;        // 2^25
constexpr float kInvScale = 1.0f / 33554432.0f;
}

// -------- scatter, LDS-resident, integer fixed-point LDS atomics --------
// Measured r8: ds_add_u32 runs ~1 cyc/lane (vs 3.5 for ANY fp32 LDS atomic
// variant: CAS loop, unsafeAtomicAdd, raw ds_add_f32 — all 116 us, r2-r5).
// 20.5M lane-atomics -> 33 us engine floor; 45 us measured = floor +
// 12.6K conflict cyc/CU (random addresses) + staging. Structure-insensitive.
__global__ __launch_bounds__(1024, 4) void kkt_scatter(
    const float* __restrict__ a_vals,
    const int*   __restrict__ a_rows,
    const int*   __restrict__ a_cols,
    const float* __restrict__ x_hat,
    const float* __restrict__ lam_hat,
    float* __restrict__ P_ax,     // [kG][kBM]
    float* __restrict__ P_at,     // [kG][kBN]
    int nnz_per)
{
    __shared__ float    s_x  [kN];  // 32 KB  instance x slice
    __shared__ float    s_lam[kM];  // 16 KB  instance lam slice
    __shared__ unsigned s_axi[kM];  // 16 KB  fixed-point accumulator
    __shared__ unsigned s_ati[kN];  // 32 KB  fixed-point accumulator (96 KB)

    const int tid = threadIdx.x;
    const int bs  = blockDim.x;
    const int k   = blockIdx.x / kG;
    const int g   = blockIdx.x % kG;
    const int row_base = k * kM;
    const int col_base = k * kN;

    // cooperative load of x/lam slices (coalesced float4) + zero accumulators
    {
        const float4* xg = reinterpret_cast<const float4*>(x_hat + col_base);
        const float4* lg = reinterpret_cast<const float4*>(lam_hat + row_base);
        float4* xs = reinterpret_cast<float4*>(s_x);
        float4* ls = reinterpret_cast<float4*>(s_lam);
        for (int j = tid; j < kN / 4; j += bs) xs[j] = xg[j];
        for (int j = tid; j < kM / 4; j += bs) ls[j] = lg[j];
        uint4 z = {0u, 0u, 0u, 0u};
        uint4* as = reinterpret_cast<uint4*>(s_axi);
        uint4* ts = reinterpret_cast<uint4*>(s_ati);
        for (int j = tid; j < kM / 4; j += bs) as[j] = z;
        for (int j = tid; j < kN / 4; j += bs) ts[j] = z;
    }
    __syncthreads();

    const int chunk = nnz_per / kG;        // 40000
    const int base  = k * nnz_per + g * chunk;
    const int nq    = chunk >> 2;
    const int qbase = base >> 2;           // base % 4 == 0 for this shape

    const float4* v4 = reinterpret_cast<const float4*>(a_vals);
    const int4*   r4 = reinterpret_cast<const int4*>(a_rows);
    const int4*   c4 = reinterpret_cast<const int4*>(a_cols);

    for (int q = tid; q < nq; q += bs) {
        float4 v = v4[qbase + q];
        int4   r = r4[qbase + q];
        int4   c = c4[qbase + q];
        int rl0 = r.x - row_base, rl1 = r.y - row_base,
            rl2 = r.z - row_base, rl3 = r.w - row_base;
        int cl0 = c.x - col_base, cl1 = c.y - col_base,
            cl2 = c.z - col_base, cl3 = c.w - col_base;
        float x0 = s_x[cl0], x1 = s_x[cl1], x2 = s_x[cl2], x3 = s_x[cl3];
        float l0 = s_lam[rl0], l1 = s_lam[rl1], l2 = s_lam[rl2], l3 = s_lam[rl3];
        int qa0 = (int)rintf(v.x * x0 * kScale);
        int qa1 = (int)rintf(v.y * x1 * kScale);
        int qa2 = (int)rintf(v.z * x2 * kScale);
        int qa3 = (int)rintf(v.w * x3 * kScale);
        int qt0 = (int)rintf(v.x * l0 * kScale);
        int qt1 = (int)rintf(v.y * l1 * kScale);
        int qt2 = (int)rintf(v.z * l2 * kScale);
        int qt3 = (int)rintf(v.w * l3 * kScale);
        atomicAdd(&s_axi[rl0], (unsigned)qa0);
        atomicAdd(&s_axi[rl1], (unsigned)qa1);
        atomicAdd(&s_axi[rl2], (unsigned)qa2);
        atomicAdd(&s_axi[rl3], (unsigned)qa3);
        atomicAdd(&s_ati[cl0], (unsigned)qt0);
        atomicAdd(&s_ati[cl1], (unsigned)qt1);
        atomicAdd(&s_ati[cl2], (unsigned)qt2);
        atomicAdd(&s_ati[cl3], (unsigned)qt3);
    }
    // scalar tail (never runs when chunk % 4 == 0; kept for safety)
    if ((chunk & 3) && g == kG - 1 && tid == 0) {
        for (int i = base + (nq << 2); i < base + chunk; ++i) {
            float v = a_vals[i];
            int qa = (int)rintf(v * s_x[a_cols[i] - col_base] * kScale);
            int qt = (int)rintf(v * s_lam[a_rows[i] - row_base] * kScale);
            atomicAdd(&s_axi[a_rows[i] - row_base], (unsigned)qa);
            atomicAdd(&s_ati[a_cols[i] - col_base], (unsigned)qt);
        }
    }
    __syncthreads();

    // convert fixed->float during the coalesced partial store
    {
        float4* pa = reinterpret_cast<float4*>(P_ax + (size_t)g * kBM + row_base);
        float4* pt = reinterpret_cast<float4*>(P_at + (size_t)g * kBN + col_base);
        const uint4* as = reinterpret_cast<const uint4*>(s_axi);
        const uint4* ts = reinterpret_cast<const uint4*>(s_ati);
        for (int j = tid; j < kM / 4; j += bs) {
            uint4 u = as[j];
            float4 o = {(float)(int)u.x * kInvScale, (float)(int)u.y * kInvScale,
                        (float)(int)u.z * kInvScale, (float)(int)u.w * kInvScale};
            pa[j] = o;
        }
        for (int j = tid; j < kN / 4; j += bs) {
            uint4 u = ts[j];
            float4 o = {(float)(int)u.x * kInvScale, (float)(int)u.y * kInvScale,
                        (float)(int)u.z * kInvScale, (float)(int)u.w * kInvScale};
            pt[j] = o;
        }
    }
}

// -------- fused reduction: per-block partial via plain store --------
// NOTE r9: folding the finalize into this kernel via device-scope ACQ_REL
// arrive counters cost +25 us (cross-XCD coherence per block arrival).
// Separate 1-us finalize dispatch is strictly better.
__device__ __forceinline__ float block_reduce_sum(float v)
{
    __shared__ float smem[16];
    int lane = threadIdx.x & 63;
    int wave = threadIdx.x >> 6;
    #pragma unroll
    for (int off = 32; off > 0; off >>= 1)
        v += __shfl_down(v, off, 64);
    if (lane == 0) smem[wave] = v;
    __syncthreads();
    float s = 0.f;
    if (threadIdx.x == 0) {
        int nw = blockDim.x >> 6;
        for (int w = 0; w < nw; ++w) s += smem[w];
    }
    return s;  // valid only on thread 0
}

__global__ void kkt_reduce(const float* __restrict__ P_ax,
                           const float* __restrict__ P_at,
                           const float* __restrict__ b_pad,
                           const float* __restrict__ lam_hat,
                           const float* __restrict__ c_pad,
                           const float* __restrict__ x_hat,
                           float* __restrict__ partials)
{
    const int mq = kBM / 4;
    const int nq = kBN / 4;
    float s1 = 0.f;                  // weight 1/((M+N)*B)
    float s2 = 0.f;                  // weight W_STAT/(N*B)
    const int stride = gridDim.x * blockDim.x;
    for (int idx = blockIdx.x * blockDim.x + threadIdx.x; idx < mq + nq; idx += stride) {
        if (idx < mq) {
            float4 ax = reinterpret_cast<const float4*>(P_ax)[idx];
            #pragma unroll
            for (int g = 1; g < kG; ++g) {
                float4 p = reinterpret_cast<const float4*>(P_ax + (size_t)g * kBM)[idx];
                ax.x += p.x; ax.y += p.y; ax.z += p.z; ax.w += p.w;
            }
            float4 bb = reinterpret_cast<const float4*>(b_pad)[idx];
            float4 ll = reinterpret_cast<const float4*>(lam_hat)[idx];
            #pragma unroll
            for (int e = 0; e < 4; ++e) {
                float axmb = (&ax.x)[e] - (&bb.x)[e];
                float l    = (&ll.x)[e];
                float rp   = fmaxf(axmb, 0.f);
                float rl   = fmaxf(-l, 0.f);
                float cm   = l * axmb;
                s1 += W_PRIMAL * rp * rp + W_DUAL * rl * rl + W_COMP * cm * cm;
            }
        } else {
            int j = idx - mq;
            float4 at = reinterpret_cast<const float4*>(P_at)[j];
            #pragma unroll
            for (int g = 1; g < kG; ++g) {
                float4 p = reinterpret_cast<const float4*>(P_at + (size_t)g * kBN)[j];
                at.x += p.x; at.y += p.y; at.z += p.z; at.w += p.w;
            }
            float4 cc = reinterpret_cast<const float4*>(c_pad)[j];
            float4 xx = reinterpret_cast<const float4*>(x_hat)[j];
            #pragma unroll
            for (int e = 0; e < 4; ++e) {
                float t  = (&at.x)[e] + (&cc.x)[e];
                float mu = fmaxf(t, 0.f);
                float st = t - mu;                 // min(t,0); dual relu(-mu)^2 == 0
                float x  = (&xx.x)[e];
                float rx = fmaxf(-x, 0.f);
                float cm = mu * x;
                s1 += W_PRIMAL * rx * rx + W_COMP * cm * cm;
                s2 += st * st;
            }
        }
    }
    const float scale1 = 1.0f / ((float)(kM + kN) * (float)kB);
    const float scale2 = W_STAT / ((float)kN * (float)kB);
    float t = block_reduce_sum(s1 * scale1 + s2 * scale2);
    if (threadIdx.x == 0) partials[blockIdx.x] = t;
}

// single block sums the kRBlocks partials
__global__ __launch_bounds__(1024) void kkt_finalize(const float* __restrict__ partials,
                                                     float* __restrict__ out)
{
    float v = partials[threadIdx.x];           // blockDim.x == kRBlocks
    float t = block_reduce_sum(v);
    if (threadIdx.x == 0) out[0] = t;
}

extern "C" void kernel_launch(void* const* d_in, const int* in_sizes, int n_in,
                              void* d_out, int out_size, void* d_ws, size_t ws_size,
                              hipStream_t stream)
{
    const float* x_hat   = (const float*)d_in[0];
    const float* lam_hat = (const float*)d_in[1];
    const float* a_vals  = (const float*)d_in[2];
    const int*   a_rows  = (const int*)d_in[3];
    const int*   a_cols  = (const int*)d_in[4];
    const float* b_pad   = (const float*)d_in[5];
    const float* c_pad   = (const float*)d_in[6];
    float* out = (float*)d_out;

    const int nnz     = in_sizes[2];
    const int nnz_per = nnz / kB;

    float* P_ax     = (float*)d_ws;                     // kG*kBM floats (4 MB)
    float* P_at     = P_ax + (size_t)kG * kBM;          // kG*kBN floats (8 MB)
    float* partials = P_at + (size_t)kG * kBN;          // kRBlocks floats

    kkt_scatter<<<dim3(kB * kG), dim3(1024), 0, stream>>>(
        a_vals, a_rows, a_cols, x_hat, lam_hat, P_ax, P_at, nnz_per);

    kkt_reduce<<<dim3(kRBlocks), dim3(256), 0, stream>>>(
        P_ax, P_at, b_pad, lam_hat, c_pad, x_hat, partials);

    kkt_finalize<<<1, dim3(kRBlocks), 0, stream>>>(partials, out);
}